// Round 8
// baseline (1536.481 us; speedup 1.0000x reference)
//
#include <hip/hip_runtime.h>

// GraphSAGE 2-layer, N=50000, E=800000, D=128.
// R8: bucket-streaming aggregation (no sort phase, no sharding, row-major).
//  - CSR-lite: hist -> single-block scan -> bucket_scatter (records only).
//  - aggregate_stream: block = 32-node bucket; streams contiguous records,
//    reads each edge row once (1 dword/lane), ds_add_f32 into 16KB LDS acc.
//  - 8 kernels total (was 11): hist, scan, scatter, convert_all,
//    agg0, gemm0, agg1, gemm1.

#define D 128
#define NBITS 5
#define BN 32        // nodes per bucket
#define GA 64        // hist/scatter block count
typedef unsigned short u16;
typedef unsigned u32;
typedef unsigned long long u64;
typedef short bf16x8 __attribute__((ext_vector_type(8)));
typedef float f32x4 __attribute__((ext_vector_type(4)));

__device__ __forceinline__ u16 f2bf(float f) {
    union { float f; unsigned u; } x;
    x.f = f;
    unsigned r = x.u + 0x7FFF + ((x.u >> 16) & 1);  // RNE
    return (u16)(r >> 16);
}
__device__ __forceinline__ float bf2f(u16 b) {
    union { unsigned u; float f; } x;
    x.u = ((unsigned)b) << 16;
    return x.f;
}

// ---------------- CSR-lite build ----------------

__global__ __launch_bounds__(1024) void bucket_hist(const int* __restrict__ dst,
                                                    int* __restrict__ Gcounts,
                                                    int E, int NB, int chunk) {
    __shared__ int cnt[1600];
    for (int i = threadIdx.x; i < NB; i += 1024) cnt[i] = 0;
    __syncthreads();
    int base = blockIdx.x * chunk;
    int end = base + chunk; if (end > E) end = E;
    for (int e = base + threadIdx.x; e < end; e += 1024)
        atomicAdd(&cnt[dst[e] >> NBITS], 1);
    __syncthreads();
    for (int b = threadIdx.x; b < NB; b += 1024)
        Gcounts[b * GA + blockIdx.x] = cnt[b];
}

// Single-block in-place exclusive scan over n values (n ~ 100k).
__global__ __launch_bounds__(1024) void scan_single(int* __restrict__ d, int n, int vpt) {
    int t = threadIdx.x;
    int base = t * vpt;
    int sum = 0;
    for (int k = 0; k < vpt; ++k) {
        int idx = base + k;
        if (idx < n) sum += d[idx];
    }
    int lane = t & 63, wid = t >> 6;
    int s = sum;
    #pragma unroll
    for (int off = 1; off < 64; off <<= 1) {
        int v = __shfl_up(s, off);
        if (lane >= off) s += v;
    }
    __shared__ int wsum[16];
    if (lane == 63) wsum[wid] = s;
    __syncthreads();
    if (wid == 0) {
        int ws = (lane < 16) ? wsum[lane] : 0;
        #pragma unroll
        for (int off = 1; off < 16; off <<= 1) {
            int v = __shfl_up(ws, off);
            if (lane >= off) ws += v;
        }
        if (lane < 16) wsum[lane] = ws;
    }
    __syncthreads();
    int run = (wid > 0 ? wsum[wid - 1] : 0) + s - sum;  // exclusive offset
    for (int k = 0; k < vpt; ++k) {
        int idx = base + k;
        if (idx < n) {
            int v = d[idx];
            d[idx] = run;
            run += v;
        }
    }
}

// Scatter packed records (dst_local<<16 | src) into bucket-ordered array.
__global__ __launch_bounds__(1024) void bucket_scatter(const int* __restrict__ src,
                                                       const int* __restrict__ dst,
                                                       const int* __restrict__ Sc,
                                                       u32* __restrict__ Ebuck,
                                                       int E, int NB, int chunk) {
    __shared__ int cur[1600];
    for (int b = threadIdx.x; b < NB; b += 1024) cur[b] = Sc[b * GA + blockIdx.x];
    __syncthreads();
    int base = blockIdx.x * chunk;
    int end = base + chunk; if (end > E) end = E;
    for (int e = base + threadIdx.x; e < end; e += 1024) {
        int d = dst[e];
        int b = d >> NBITS;
        int pos = atomicAdd(&cur[b], 1);
        Ebuck[pos] = ((u32)(d & (BN - 1)) << 16) | (u32)src[e];
    }
}

// ---------------- fp32 -> bf16 convert (x + 4 weights, one kernel) ----------
__global__ void convert_all(const float* __restrict__ x,
                            const float* __restrict__ w0, const float* __restrict__ w1,
                            const float* __restrict__ w2, const float* __restrict__ w3,
                            u16* __restrict__ xb,
                            u16* __restrict__ o0, u16* __restrict__ o1,
                            u16* __restrict__ o2, u16* __restrict__ o3,
                            int xQuads) {
    int i = blockIdx.x * 256 + threadIdx.x;
    const float* in;
    u16* out;
    int j;
    if (i < xQuads) {
        in = x; out = xb; j = i;
    } else {
        int t = i - xQuads;
        int m = t >> 12;            // D*D/4 = 4096 per weight
        if (m > 3) return;
        j = t & 4095;
        in = (m == 0) ? w0 : (m == 1) ? w1 : (m == 2) ? w2 : w3;
        out = (m == 0) ? o0 : (m == 1) ? o1 : (m == 2) ? o2 : o3;
    }
    float4 v = *(const float4*)&in[j * 4];
    ushort4 o;
    o.x = f2bf(v.x); o.y = f2bf(v.y); o.z = f2bf(v.z); o.w = f2bf(v.w);
    *(ushort4*)&out[j * 4] = o;
}

// ---------------- bucket-streaming mean aggregation ----------------
// Block = bucket of BN=32 nodes; its ~512 records are contiguous [start,end).
// Wave processes 4 edges per iter (stride 16 across 4 waves): broadcast record
// loads, full 256B row gather (1 dword/lane), 2x ds_add_f32 per lane per edge.
__global__ __launch_bounds__(256) void aggregate_stream(const u16* __restrict__ xb,
                                                        const u32* __restrict__ Ebuck,
                                                        const int* __restrict__ Sc,
                                                        u16* __restrict__ aggb,
                                                        int E, int N, int NB) {
    __shared__ float acc[BN * D];   // 16 KB
    __shared__ int deg[BN];
    const int b = blockIdx.x;
    const int tid = threadIdx.x;
    const int start = Sc[b * GA];
    const int end = (b + 1 < NB) ? Sc[(b + 1) * GA] : E;

    #pragma unroll
    for (int i = 0; i < BN * D / 4 / 256; ++i)
        *(float4*)&acc[(i * 256 + tid) * 4] = make_float4(0.f, 0.f, 0.f, 0.f);
    if (tid < BN) deg[tid] = 0;
    __syncthreads();

    const int lane = tid & 63;
    const int wave = tid >> 6;
    const int fo = lane * 2;   // feature pair this lane owns

    int e = start + wave * 4;
    for (; e + 4 <= end; e += 16) {
        u32 r0 = Ebuck[e], r1 = Ebuck[e + 1], r2 = Ebuck[e + 2], r3 = Ebuck[e + 3];
        int d0 = r0 >> 16, d1 = r1 >> 16, d2 = r2 >> 16, d3 = r3 >> 16;
        u32 v0 = *(const u32*)&xb[(size_t)(r0 & 0xFFFF) * D + fo];
        u32 v1 = *(const u32*)&xb[(size_t)(r1 & 0xFFFF) * D + fo];
        u32 v2 = *(const u32*)&xb[(size_t)(r2 & 0xFFFF) * D + fo];
        u32 v3 = *(const u32*)&xb[(size_t)(r3 & 0xFFFF) * D + fo];
        if (lane < 4) {
            int dd = (lane == 0) ? d0 : (lane == 1) ? d1 : (lane == 2) ? d2 : d3;
            atomicAdd(&deg[dd], 1);
        }
        atomicAdd(&acc[d0 * D + fo],     bf2f((u16)(v0 & 0xFFFF)));
        atomicAdd(&acc[d0 * D + fo + 1], bf2f((u16)(v0 >> 16)));
        atomicAdd(&acc[d1 * D + fo],     bf2f((u16)(v1 & 0xFFFF)));
        atomicAdd(&acc[d1 * D + fo + 1], bf2f((u16)(v1 >> 16)));
        atomicAdd(&acc[d2 * D + fo],     bf2f((u16)(v2 & 0xFFFF)));
        atomicAdd(&acc[d2 * D + fo + 1], bf2f((u16)(v2 >> 16)));
        atomicAdd(&acc[d3 * D + fo],     bf2f((u16)(v3 & 0xFFFF)));
        atomicAdd(&acc[d3 * D + fo + 1], bf2f((u16)(v3 >> 16)));
    }
    for (; e < end; ++e) {
        u32 r0 = Ebuck[e];
        int d0 = r0 >> 16;
        u32 v0 = *(const u32*)&xb[(size_t)(r0 & 0xFFFF) * D + fo];
        if (lane == 0) atomicAdd(&deg[d0], 1);
        atomicAdd(&acc[d0 * D + fo],     bf2f((u16)(v0 & 0xFFFF)));
        atomicAdd(&acc[d0 * D + fo + 1], bf2f((u16)(v0 >> 16)));
    }
    __syncthreads();

    // mean + bf16 store: thread t -> node t>>3, feats (t&7)*16..+16 (32B)
    int node = tid >> 3, q = tid & 7;
    int gnode = b * BN + node;
    if (gnode < N) {
        int dg = deg[node];
        if (dg < 1) dg = 1;
        float inv = 1.0f / (float)dg;
        const float* ap = &acc[node * D + q * 16];
        u64* dp = (u64*)&aggb[(size_t)gnode * D + q * 16];
        #pragma unroll
        for (int g = 0; g < 4; ++g) {
            u64 v = (u64)f2bf(ap[g * 4 + 0] * inv)
                  | ((u64)f2bf(ap[g * 4 + 1] * inv) << 16)
                  | ((u64)f2bf(ap[g * 4 + 2] * inv) << 32)
                  | ((u64)f2bf(ap[g * 4 + 3] * inv) << 48);
            dp[g] = v;
        }
    }
}

// ---------------- dual-GEMM via MFMA (row-major) ----------------
#define LSTR 136

__global__ __launch_bounds__(256) void gemm_mfma(const u16* __restrict__ Aroot,
                                                 const u16* __restrict__ Wr,
                                                 const u16* __restrict__ Agg,
                                                 const u16* __restrict__ Wl,
                                                 const float* __restrict__ bias,
                                                 void* __restrict__ out,
                                                 int n, int mode) {  // mode1: relu+bf16 out
    __shared__ __align__(16) u16 Lr[64 * LSTR];
    __shared__ __align__(16) u16 Lg[64 * LSTR];
    const int tid = threadIdx.x;
    const int n0 = blockIdx.x * 64;

    {
        int row = tid >> 4;
        int c = (tid & 15) * 8;
        #pragma unroll
        for (int p = 0; p < 4; ++p) {
            int r = p * 16 + row;
            int g = n0 + r;
            float4 vr = make_float4(0.f, 0.f, 0.f, 0.f);
            float4 vg = make_float4(0.f, 0.f, 0.f, 0.f);
            if (g < n) {
                vr = *(const float4*)&Aroot[(size_t)g * D + c];
                vg = *(const float4*)&Agg[(size_t)g * D + c];
            }
            *(float4*)&Lr[r * LSTR + c] = vr;
            *(float4*)&Lg[r * LSTR + c] = vg;
        }
    }

    const int wave = tid >> 6;
    const int lane = tid & 63;
    const int quad = lane >> 4;
    const int l16 = lane & 15;

    bf16x8 wr[2][4], wl[2][4];
    #pragma unroll
    for (int mt = 0; mt < 2; ++mt) {
        int jrow = wave * 32 + mt * 16 + l16;
        #pragma unroll
        for (int kb = 0; kb < 4; ++kb) {
            wr[mt][kb] = *(const bf16x8*)&Wr[jrow * D + kb * 32 + quad * 8];
            wl[mt][kb] = *(const bf16x8*)&Wl[jrow * D + kb * 32 + quad * 8];
        }
    }

    __syncthreads();

    f32x4 acc[4][2];
    #pragma unroll
    for (int it = 0; it < 4; ++it)
        #pragma unroll
        for (int mt = 0; mt < 2; ++mt)
            acc[it][mt] = (f32x4){0.f, 0.f, 0.f, 0.f};

    #pragma unroll
    for (int it = 0; it < 4; ++it) {
        int base = (it * 16 + l16) * LSTR + quad * 8;
        #pragma unroll
        for (int kb = 0; kb < 4; ++kb) {
            bf16x8 bx = *(const bf16x8*)&Lr[base + kb * 32];
            bf16x8 bg = *(const bf16x8*)&Lg[base + kb * 32];
            #pragma unroll
            for (int mt = 0; mt < 2; ++mt) {
                acc[it][mt] = __builtin_amdgcn_mfma_f32_16x16x32_bf16(wr[mt][kb], bx, acc[it][mt], 0, 0, 0);
                acc[it][mt] = __builtin_amdgcn_mfma_f32_16x16x32_bf16(wl[mt][kb], bg, acc[it][mt], 0, 0, 0);
            }
        }
    }

    #pragma unroll
    for (int it = 0; it < 4; ++it) {
        int i = n0 + it * 16 + l16;
        if (i < n) {
            #pragma unroll
            for (int mt = 0; mt < 2; ++mt) {
                int j0 = wave * 32 + mt * 16 + quad * 4;
                float4 bv = *(const float4*)&bias[j0];
                float o0 = acc[it][mt][0] + bv.x;
                float o1 = acc[it][mt][1] + bv.y;
                float o2 = acc[it][mt][2] + bv.z;
                float o3 = acc[it][mt][3] + bv.w;
                if (mode) {
                    o0 = fmaxf(o0, 0.f); o1 = fmaxf(o1, 0.f);
                    o2 = fmaxf(o2, 0.f); o3 = fmaxf(o3, 0.f);
                    ushort4 ob;
                    ob.x = f2bf(o0); ob.y = f2bf(o1); ob.z = f2bf(o2); ob.w = f2bf(o3);
                    *(ushort4*)&((u16*)out)[(size_t)i * D + j0] = ob;
                } else {
                    float4 of = make_float4(o0, o1, o2, o3);
                    *(float4*)&((float*)out)[(size_t)i * D + j0] = of;
                }
            }
        }
    }
}

// ---------------- launch ----------------

extern "C" void kernel_launch(void* const* d_in, const int* in_sizes, int n_in,
                              void* d_out, int out_size, void* d_ws, size_t ws_size,
                              hipStream_t stream) {
    const float* x = (const float*)d_in[0];
    const int* edge = (const int*)d_in[1];
    const float* Wl0 = (const float*)d_in[2];
    const float* Wr0 = (const float*)d_in[3];
    const float* b0 = (const float*)d_in[4];
    const float* Wl1 = (const float*)d_in[5];
    const float* Wr1 = (const float*)d_in[6];
    const float* b1 = (const float*)d_in[7];

    const int N = in_sizes[0] / D;
    const int E = in_sizes[1] / 2;
    const int* src = edge;
    const int* dst = edge + E;

    char* ws = (char*)d_ws;
    size_t off = 0;
    auto alloc = [&](size_t bytes) {
        char* p = ws + off;
        off += (bytes + 255) & ~(size_t)255;
        return p;
    };
    u32* Ebuck = (u32*)alloc((size_t)E * 4);
    u16* xb = (u16*)alloc((size_t)N * D * 2);
    u16* hb = (u16*)alloc((size_t)N * D * 2);
    u16* aggb = (u16*)alloc((size_t)N * D * 2);
    u16* Wl0b = (u16*)alloc((size_t)D * D * 2);
    u16* Wr0b = (u16*)alloc((size_t)D * D * 2);
    u16* Wl1b = (u16*)alloc((size_t)D * D * 2);
    u16* Wr1b = (u16*)alloc((size_t)D * D * 2);
    const int NB = (N + BN - 1) / BN;
    const int scanN = NB * GA;
    int* Sc = (int*)alloc((size_t)scanN * 4);   // Gcounts, scanned in place

    (void)ws_size; (void)n_in; (void)out_size;

    const int chunk = (E + GA - 1) / GA;
    const int vpt = (scanN + 1023) / 1024;

    // CSR-lite build
    bucket_hist<<<GA, 1024, 0, stream>>>(dst, Sc, E, NB, chunk);
    scan_single<<<1, 1024, 0, stream>>>(Sc, scanN, vpt);
    bucket_scatter<<<GA, 1024, 0, stream>>>(src, dst, Sc, Ebuck, E, NB, chunk);

    // converts (x row-major bf16 + 4 weights)
    int xQuads = N * D / 4;
    int cvBlocks = (xQuads + 4 * (D * D / 4) + 255) / 256;
    convert_all<<<cvBlocks, 256, 0, stream>>>(x, Wl0, Wr0, Wl1, Wr1,
                                              xb, Wl0b, Wr0b, Wl1b, Wr1b, xQuads);

    int gemmBlocks = (N + 63) / 64;

    // layer 0
    aggregate_stream<<<NB, 256, 0, stream>>>(xb, Ebuck, Sc, aggb, E, N, NB);
    gemm_mfma<<<gemmBlocks, 256, 0, stream>>>(xb, Wr0b, aggb, Wl0b, b0, hb, N, 1);
    // layer 1
    aggregate_stream<<<NB, 256, 0, stream>>>(hb, Ebuck, Sc, aggb, E, N, NB);
    gemm_mfma<<<gemmBlocks, 256, 0, stream>>>(hb, Wr1b, aggb, Wl1b, b1, d_out, N, 0);
}